// Round 4
// baseline (4316.644 us; speedup 1.0000x reference)
//
#include <hip/hip_runtime.h>
#include <hip/hip_bf16.h>

#define NUM_USER 300000
#define NUM_ITEM 200000
#define NTOT     (NUM_USER + NUM_ITEM)       // 500000
#define D        64
#define RPB      128                          // rows per bucket
#define NB       ((NTOT + RPB - 1) / RPB)     // 3907
#define NS       4                            // sub-cursors per bucket
#define NBS      (NB * NS)                    // 15628
#define PAD      16                           // ints per counter (64B line)
#define GBLK     ((NTOT + 63) / 64)           // 7813 gemm blocks

typedef __attribute__((ext_vector_type(8))) short bf16x8;
typedef __attribute__((ext_vector_type(4))) float f32x4;

__device__ __forceinline__ short f2bf(float f) {
    unsigned u = __float_as_uint(f);
    u += 0x7FFFu + ((u >> 16) & 1u);   // round-to-nearest-even
    return (short)(u >> 16);
}

// ---------- 1. histogram of (bucket, sub) counts ----------
// grid kept small (128): merge atomics = 128*NBS = 2M, edge counting in LDS.
__global__ __launch_bounds__(512) void hist_kernel(
    const int* __restrict__ rows, int* __restrict__ gcnt, int nnz)
{
    __shared__ int lcnt[NBS];                 // 62.5 KB
    for (int i = threadIdx.x; i < NBS; i += 512) lcnt[i] = 0;
    __syncthreads();
    int stride = gridDim.x * 512;
    for (int e = blockIdx.x * 512 + threadIdx.x; e < nnz; e += stride) {
        int r = rows[e];
        int bs = ((r >> 7) << 2) | ((e >> 12) & 3);
        atomicAdd(&lcnt[bs], 1);
    }
    __syncthreads();
    for (int i = threadIdx.x; i < NBS; i += 512) {
        int c = lcnt[i];
        if (c) atomicAdd(&gcnt[i * PAD], c);
    }
}

// ---------- 2. exclusive scan of NBS counts (single block) ----------
__global__ __launch_bounds__(1024) void scan_kernel(
    const int* __restrict__ gcnt, int* __restrict__ start,
    int* __restrict__ cursor, int nnz)
{
    __shared__ int s[1024];
    int t = threadIdx.x;
    int loc[16]; int sum = 0;
    #pragma unroll
    for (int j = 0; j < 16; j++) {
        int i = t * 16 + j;
        int c = (i < NBS) ? gcnt[i * PAD] : 0;
        loc[j] = sum; sum += c;
    }
    s[t] = sum; __syncthreads();
    int v = sum;
    for (int off = 1; off < 1024; off <<= 1) {
        int add = (t >= off) ? s[t - off] : 0;
        __syncthreads();
        s[t] += add;
        __syncthreads();
    }
    int base = s[t] - v;
    #pragma unroll
    for (int j = 0; j < 16; j++) {
        int i = t * 16 + j;
        if (i < NBS) { int p = base + loc[j]; start[i] = p; cursor[i * PAD] = p; }
    }
    if (t == 0) start[NBS] = nnz;
}

// ---------- 3. bin-scatter fat records { (lrow<<19)|col , val } ----------
__global__ __launch_bounds__(256) void scatter_fat(
    const int* __restrict__ rows, const int* __restrict__ cols,
    const float* __restrict__ vals, int* __restrict__ cursor,
    uint2* __restrict__ recs, int nnz)
{
    int stride = gridDim.x * 256;
    for (int e = blockIdx.x * 256 + threadIdx.x; e < nnz; e += stride) {
        int r = rows[e];
        int bs = ((r >> 7) << 2) | ((e >> 12) & 3);
        int pos = atomicAdd(&cursor[bs * PAD], 1);
        uint2 rec;
        rec.x = ((unsigned)(r & 127) << 19) | (unsigned)cols[e];
        rec.y = __float_as_uint(vals[e]);
        recs[pos] = rec;
    }
}

// ---------- 4a. EW = all_emb @ w, stored bf16 (gather table) ----------
__global__ __launch_bounds__(256) void gemm_ew(
    const float* __restrict__ users_emb, const float* __restrict__ items_emb,
    const float* __restrict__ w, unsigned short* __restrict__ ew)
{
    __shared__ short wt[D * 72];              // w^T bf16, padded
    __shared__ unsigned short tile[64 * D];   // 8 KB C-layout transform
    int tid = threadIdx.x;
    for (int i = tid; i < D * D; i += 256) {
        int k = i >> 6, n = i & 63;
        wt[n * 72 + k] = f2bf(w[i]);
    }
    __syncthreads();
    int wid = tid >> 6, lane = tid & 63;
    int quad = lane >> 4, mrow = lane & 15;
    int row0 = blockIdx.x * 64 + wid * 16;
    int r = row0 + mrow; if (r >= NTOT) r = NTOT - 1;   // tail clamp (pad rows unread)
    const float* arow = (r < NUM_USER) ? users_emb + (size_t)r * D
                                       : items_emb + (size_t)(r - NUM_USER) * D;
    bf16x8 a[2];
    #pragma unroll
    for (int kh = 0; kh < 2; kh++) {
        int kb = kh * 32 + quad * 8;
        float4 f0 = *(const float4*)(arow + kb);
        float4 f1 = *(const float4*)(arow + kb + 4);
        bf16x8 t;
        t[0] = f2bf(f0.x); t[1] = f2bf(f0.y); t[2] = f2bf(f0.z); t[3] = f2bf(f0.w);
        t[4] = f2bf(f1.x); t[5] = f2bf(f1.y); t[6] = f2bf(f1.z); t[7] = f2bf(f1.w);
        a[kh] = t;
    }
    #pragma unroll
    for (int ct = 0; ct < 4; ct++) {
        f32x4 accv = {0.f, 0.f, 0.f, 0.f};
        int n = ct * 16 + mrow;
        #pragma unroll
        for (int kh = 0; kh < 2; kh++) {
            bf16x8 bv = *(bf16x8*)(wt + n * 72 + kh * 32 + quad * 8);
            accv = __builtin_amdgcn_mfma_f32_16x16x32_bf16(a[kh], bv, accv, 0, 0, 0);
        }
        #pragma unroll
        for (int rr = 0; rr < 4; rr++)
            tile[(wid * 16 + quad * 4 + rr) * D + ct * 16 + mrow] = (unsigned short)f2bf(accv[rr]);
    }
    __syncthreads();
    ushort4* dst = (ushort4*)(ew + (size_t)blockIdx.x * 64 * D);
    const ushort4* srcp = (const ushort4*)tile;
    #pragma unroll
    for (int i = 0; i < 4; i++) dst[tid + i * 256] = srcp[tid + i * 256];
}

// ---------- 5a. accumulate bf16 EW gathers into LDS, fused leaky_relu ----------
#define UN 8
__global__ __launch_bounds__(256, 5) void accum_ew(
    const unsigned short* __restrict__ ew, const uint2* __restrict__ recs,
    const int* __restrict__ start, float* __restrict__ out)
{
    __shared__ float acc[RPB * D];            // 32 KB -> 5 blocks/CU
    int tid = threadIdx.x;
    f32x4 z = {0.f, 0.f, 0.f, 0.f};
    for (int i = tid; i < RPB * D / 4; i += 256) ((f32x4*)acc)[i] = z;
    __syncthreads();
    int b = blockIdx.x;
    int s0 = start[b * NS], s1 = start[b * NS + NS];
    int lane = tid & 63, wid = tid >> 6;
    int per = (s1 - s0 + 3) >> 2;
    int a0 = s0 + wid * per;
    int a1 = a0 + per; if (a1 > s1) a1 = s1;
    float* accl = acc + lane;
    int idx = a0;
    for (; idx + UN <= a1; idx += UN) {
        uint2 r[UN];
        #pragma unroll
        for (int u = 0; u < UN; u++) r[u] = recs[idx + u];
        float g[UN];
        #pragma unroll
        for (int u = 0; u < UN; u++) {
            unsigned c = r[u].x & 0x7FFFFu;
            g[u] = __uint_as_float((unsigned)ew[(size_t)c * D + lane] << 16);
        }
        #pragma unroll
        for (int u = 0; u < UN; u++) {
            int lr = (int)(r[u].x >> 19);
            atomicAdd(accl + lr * D, __uint_as_float(r[u].y) * g[u]);
        }
    }
    for (; idx < a1; idx++) {
        uint2 r0 = recs[idx];
        unsigned c = r0.x & 0x7FFFFu;
        float g = __uint_as_float((unsigned)ew[(size_t)c * D + lane] << 16);
        atomicAdd(accl + (int)(r0.x >> 19) * D, __uint_as_float(r0.y) * g);
    }
    __syncthreads();
    int row0 = b * RPB;
    int nr = NTOT - row0; if (nr > RPB) nr = RPB;
    f32x4* dst = (f32x4*)(out + (size_t)row0 * D);
    for (int i = tid; i < nr * (D / 4); i += 256) {
        f32x4 t = ((f32x4*)acc)[i];
        #pragma unroll
        for (int j = 0; j < 4; j++) t[j] = t[j] > 0.f ? t[j] : 0.2f * t[j];
        dst[i] = t;
    }
}

// ---------- 4b/5b. fallback (small ws): fp32 gather + in-place GEMM ----------
__global__ __launch_bounds__(256, 5) void accum_raw(
    const float* __restrict__ users_emb, const float* __restrict__ items_emb,
    const uint2* __restrict__ recs, const int* __restrict__ start,
    float* __restrict__ out)
{
    __shared__ float acc[RPB * D];
    int tid = threadIdx.x;
    f32x4 z = {0.f, 0.f, 0.f, 0.f};
    for (int i = tid; i < RPB * D / 4; i += 256) ((f32x4*)acc)[i] = z;
    __syncthreads();
    int b = blockIdx.x;
    int s0 = start[b * NS], s1 = start[b * NS + NS];
    int lane = tid & 63, wid = tid >> 6;
    int per = (s1 - s0 + 3) >> 2;
    int a0 = s0 + wid * per;
    int a1 = a0 + per; if (a1 > s1) a1 = s1;
    float* accl = acc + lane;
    int idx = a0;
    for (; idx + UN <= a1; idx += UN) {
        uint2 r[UN];
        #pragma unroll
        for (int u = 0; u < UN; u++) r[u] = recs[idx + u];
        float g[UN];
        #pragma unroll
        for (int u = 0; u < UN; u++) {
            unsigned c = r[u].x & 0x7FFFFu;
            const float* src = (c < NUM_USER) ? users_emb + (size_t)c * D
                                              : items_emb + (size_t)(c - NUM_USER) * D;
            g[u] = src[lane];
        }
        #pragma unroll
        for (int u = 0; u < UN; u++) {
            int lr = (int)(r[u].x >> 19);
            atomicAdd(accl + lr * D, __uint_as_float(r[u].y) * g[u]);
        }
    }
    for (; idx < a1; idx++) {
        uint2 r0 = recs[idx];
        unsigned c = r0.x & 0x7FFFFu;
        const float* src = (c < NUM_USER) ? users_emb + (size_t)c * D
                                          : items_emb + (size_t)(c - NUM_USER) * D;
        atomicAdd(accl + (int)(r0.x >> 19) * D, __uint_as_float(r0.y) * src[lane]);
    }
    __syncthreads();
    int row0 = b * RPB;
    int nr = NTOT - row0; if (nr > RPB) nr = RPB;
    f32x4* dst = (f32x4*)(out + (size_t)row0 * D);
    for (int i = tid; i < nr * (D / 4); i += 256) dst[i] = ((f32x4*)acc)[i];
}

__global__ __launch_bounds__(256) void gemm_inplace(
    float* __restrict__ out, const float* __restrict__ w)
{
    __shared__ short wt[D * 72];
    __shared__ float tile[64 * D];   // 16 KB
    int tid = threadIdx.x;
    for (int i = tid; i < D * D; i += 256) {
        int k = i >> 6, n = i & 63;
        wt[n * 72 + k] = f2bf(w[i]);
    }
    __syncthreads();
    int wid = tid >> 6, lane = tid & 63;
    int quad = lane >> 4, mrow = lane & 15;
    int row0 = blockIdx.x * 64 + wid * 16;
    int r = row0 + mrow; if (r >= NTOT) r = NTOT - 1;
    const float* arow = out + (size_t)r * D;
    bf16x8 a[2];
    #pragma unroll
    for (int kh = 0; kh < 2; kh++) {
        int kb = kh * 32 + quad * 8;
        float4 f0 = *(const float4*)(arow + kb);
        float4 f1 = *(const float4*)(arow + kb + 4);
        bf16x8 t;
        t[0] = f2bf(f0.x); t[1] = f2bf(f0.y); t[2] = f2bf(f0.z); t[3] = f2bf(f0.w);
        t[4] = f2bf(f1.x); t[5] = f2bf(f1.y); t[6] = f2bf(f1.z); t[7] = f2bf(f1.w);
        a[kh] = t;
    }
    #pragma unroll
    for (int ct = 0; ct < 4; ct++) {
        f32x4 accv = {0.f, 0.f, 0.f, 0.f};
        int n = ct * 16 + mrow;
        #pragma unroll
        for (int kh = 0; kh < 2; kh++) {
            bf16x8 bv = *(bf16x8*)(wt + n * 72 + kh * 32 + quad * 8);
            accv = __builtin_amdgcn_mfma_f32_16x16x32_bf16(a[kh], bv, accv, 0, 0, 0);
        }
        #pragma unroll
        for (int rr = 0; rr < 4; rr++) {
            float vv = accv[rr];
            vv = vv > 0.f ? vv : 0.2f * vv;
            tile[(wid * 16 + quad * 4 + rr) * D + ct * 16 + mrow] = vv;
        }
    }
    __syncthreads();
    int base_row = blockIdx.x * 64;
    int nrow = NTOT - base_row; if (nrow > 64) nrow = 64;
    f32x4* dst = (f32x4*)(out + (size_t)base_row * D);
    const f32x4* srcp = (const f32x4*)tile;
    for (int i = tid; i < nrow * (D / 4); i += 256) dst[i] = srcp[i];
}

extern "C" void kernel_launch(void* const* d_in, const int* in_sizes, int n_in,
                              void* d_out, int out_size, void* d_ws, size_t ws_size,
                              hipStream_t stream) {
    const float* users_emb = (const float*)d_in[0];
    const float* items_emb = (const float*)d_in[1];
    const float* vals      = (const float*)d_in[2];
    const float* w         = (const float*)d_in[3];
    const int*   rows      = (const int*)d_in[4];
    const int*   cols      = (const int*)d_in[5];
    float* out = (float*)d_out;
    int nnz = in_sizes[2];

    // ws layout: gcnt@0 (1MB), cursor@1MB (1MB), start@2MB (64KB)
    //   EW path:  ew@4MB (64.01MB), recs@68MB (80MB)  -> needs ~151.3 MB
    //   fallback: recs@2.25MB (80MB)                   -> 82.3 MB (known safe)
    char* wsb = (char*)d_ws;
    int* gcnt   = (int*)(wsb);
    int* cursor = (int*)(wsb + (1ull << 20));
    int* start  = (int*)(wsb + (2ull << 20));
    unsigned short* ew = (unsigned short*)(wsb + (4ull << 20));
    size_t recs_off_ew = 68ull << 20;
    bool use_ew = ws_size >= recs_off_ew + (size_t)nnz * sizeof(uint2);
    uint2* recs = (uint2*)(wsb + (use_ew ? recs_off_ew : (9ull << 18)));

    hipMemsetAsync(gcnt, 0, (size_t)NBS * PAD * sizeof(int), stream);
    if (use_ew)
        gemm_ew<<<GBLK, 256, 0, stream>>>(users_emb, items_emb, w, ew);
    hist_kernel<<<128, 512, 0, stream>>>(rows, gcnt, nnz);
    scan_kernel<<<1, 1024, 0, stream>>>(gcnt, start, cursor, nnz);
    scatter_fat<<<2048, 256, 0, stream>>>(rows, cols, vals, cursor, recs, nnz);
    if (use_ew) {
        accum_ew<<<NB, 256, 0, stream>>>(ew, recs, start, out);
    } else {
        accum_raw<<<NB, 256, 0, stream>>>(users_emb, items_emb, recs, start, out);
        gemm_inplace<<<GBLK, 256, 0, stream>>>(out, w);
    }
}